// Round 4
// baseline (1455.722 us; speedup 1.0000x reference)
//
#include <hip/hip_runtime.h>

#define DEV __device__ __forceinline__

typedef __attribute__((ext_vector_type(8))) short s16x8;   // 8 bf16 (4 VGPRs) MFMA A/B frag
typedef __attribute__((ext_vector_type(4))) float f32x4;   // MFMA C/D frag
typedef __attribute__((ext_vector_type(4))) unsigned short u16x4;

#define BTOK 8192   // B*S
#define DD   1024
#define FF   4096
#define EE   4

// round-to-nearest-even f32 -> bf16 bits
DEV unsigned short f2bf(float f) {
  unsigned int u = __float_as_uint(f);
  unsigned int r = (u + 0x7FFFu + ((u >> 16) & 1u)) >> 16;
  return (unsigned short)r;
}

// async global->LDS, 16 bytes/lane; LDS dest = wave-uniform base + lane*16
DEV void gld_lds16(const void* g, void* l) {
  __builtin_amdgcn_global_load_lds(
      (const __attribute__((address_space(1))) unsigned int*)g,
      (__attribute__((address_space(3))) unsigned int*)l,
      16, 0, 0);
}

// ---------------------------------------------------------------------------
// 128x128 bf16 MFMA tile mainloop, group-major LDS layout (0 bank conflicts,
// verified R3). A rows optionally gathered via idxA (only mode-0 fallback).
// ---------------------------------------------------------------------------
DEV void gemm_tile(const unsigned short* __restrict__ A, const int* idxA, int ldA,
                   const unsigned short* __restrict__ B, int ldB,
                   int kStart, int kLen, int tileM, int tileN,
                   unsigned short* As, unsigned short* Bs,
                   f32x4 (&acc)[4][4]) {
  const int t    = threadIdx.x;
  const int lane = t & 63;
  const int wv   = t >> 6;
  const int wm   = (wv & 1) << 6;
  const int wn   = (wv >> 1) << 6;
  const int m16  = lane & 15;
  const int quad = lane >> 4;

  const int r  = t & 127;   // staged row
  const int g0 = t >> 7;    // k-group 0/1; second chunk is g0+2

  const int rowA = idxA ? idxA[tileM + r] : (tileM + r);
  const unsigned short* A0 = A + (size_t)rowA * ldA + kStart + g0 * 8;
  const unsigned short* B0 = B + (size_t)(tileN + r) * ldB + kStart + g0 * 8;

  for (int k0 = 0; k0 < kLen; k0 += 32) {
    __syncthreads();
    gld_lds16(A0 + k0,      As + t * 8);
    gld_lds16(A0 + k0 + 16, As + (t + 256) * 8);
    gld_lds16(B0 + k0,      Bs + t * 8);
    gld_lds16(B0 + k0 + 16, Bs + (t + 256) * 8);
    __syncthreads();

    s16x8 aF[4], bF[4];
#pragma unroll
    for (int i = 0; i < 4; ++i) {
      aF[i] = *(const s16x8*)(As + (quad << 10) + ((wm + i * 16 + m16) << 3));
      bF[i] = *(const s16x8*)(Bs + (quad << 10) + ((wn + i * 16 + m16) << 3));
    }
#pragma unroll
    for (int mt = 0; mt < 4; ++mt)
#pragma unroll
      for (int nt = 0; nt < 4; ++nt)
        acc[mt][nt] = __builtin_amdgcn_mfma_f32_16x16x32_bf16(
            aF[mt], bF[nt], acc[mt][nt], 0, 0, 0);
  }
}

// ---------------------------------------------------------------------------
// GEMM1: h[p][f] = bf16( sc[p] * relu( A[p]@W1[e] + b1[e][f] ) ), p < npad[e].
// A = xcomp (dense compact rows, idxA=null) or xb gathered (mode 0).
// ---------------------------------------------------------------------------
__global__ __launch_bounds__(256) void gemm1_kernel(
    const unsigned short* __restrict__ A,
    const int* __restrict__ idxA,            // null in modes 1/2
    const unsigned short* __restrict__ W1T,  // [EE][FF][DD]
    const float* __restrict__ b1,            // [EE][FF]
    const float* __restrict__ sc,            // [EE][BTOK] compact scales
    const int* __restrict__ nArr,            // [0..3]=npad, [4..7]=n
    unsigned short* __restrict__ h,          // [BTOK][FF]
    int e) {
  __shared__ __attribute__((aligned(16))) unsigned short As[128 * 32];
  __shared__ __attribute__((aligned(16))) unsigned short Bs[128 * 32];

  const int np    = nArr[e];
  const int tileM = blockIdx.y * 128;
  if (tileM >= np) return;
  const int tileN = blockIdx.x * 128;

  f32x4 acc[4][4];
#pragma unroll
  for (int i = 0; i < 4; ++i)
#pragma unroll
    for (int j = 0; j < 4; ++j) acc[i][j] = f32x4{0.f, 0.f, 0.f, 0.f};

  gemm_tile(A, idxA, DD, W1T + (size_t)e * FF * DD, DD,
            0, DD, tileM, tileN, As, Bs, acc);

  const int t = threadIdx.x;
  const int lane = t & 63, wv = t >> 6;
  const int wm = (wv & 1) << 6, wn = (wv >> 1) << 6;
  const int m16 = lane & 15, quad = lane >> 4;
  const float* b1e = b1 + e * FF;
  const float* sce = sc + e * BTOK;

#pragma unroll
  for (int mt = 0; mt < 4; ++mt) {
    const int row = tileM + wm + mt * 16 + quad * 4;
    const f32x4 cv = *(const f32x4*)(sce + row);
#pragma unroll
    for (int nt = 0; nt < 4; ++nt) {
      const int col = tileN + wn + nt * 16 + m16;
      const float bb = b1e[col];
      f32x4 v = acc[mt][nt];
      h[(size_t)(row + 0) * FF + col] = f2bf(fmaxf(v[0] + bb, 0.f) * cv[0]);
      h[(size_t)(row + 1) * FF + col] = f2bf(fmaxf(v[1] + bb, 0.f) * cv[1]);
      h[(size_t)(row + 2) * FF + col] = f2bf(fmaxf(v[2] + bb, 0.f) * cv[2]);
      h[(size_t)(row + 3) * FF + col] = f2bf(fmaxf(v[3] + bb, 0.f) * cv[3]);
    }
  }
}

// ---------------------------------------------------------------------------
// GEMM2: compact rows, K split into zSplit slices (grid z).
// atomicMode=0: plain stores into oE[z][p][DD]  (no atomics, slices summed in
//               scatter). atomicMode=1: unsafeAtomicAdd direct to out (mode 0).
// ---------------------------------------------------------------------------
__global__ __launch_bounds__(256) void gemm2_kernel(
    const unsigned short* __restrict__ h,    // [BTOK][FF]
    const unsigned short* __restrict__ W2T,  // [EE][DD][FF]
    const int* __restrict__ idx,             // [EE][BTOK]
    const int* __restrict__ nArr,
    float* __restrict__ oE,                  // [zSplit][BTOK][DD] (mode 1/2)
    float* __restrict__ out,                 // [BTOK][DD]       (mode 0)
    int e, int kLen, int atomicMode) {
  __shared__ __attribute__((aligned(16))) unsigned short As[128 * 32];
  __shared__ __attribute__((aligned(16))) unsigned short Bs[128 * 32];

  const int np    = nArr[e];
  const int tileM = blockIdx.y * 128;
  if (tileM >= np) return;
  const int tileN  = blockIdx.x * 128;
  const int kStart = blockIdx.z * kLen;

  f32x4 acc[4][4];
#pragma unroll
  for (int i = 0; i < 4; ++i)
#pragma unroll
    for (int j = 0; j < 4; ++j) acc[i][j] = f32x4{0.f, 0.f, 0.f, 0.f};

  gemm_tile(h, (const int*)nullptr, FF, W2T + (size_t)e * DD * FF, FF,
            kStart, kLen, tileM, tileN, As, Bs, acc);

  const int t = threadIdx.x;
  const int lane = t & 63, wv = t >> 6;
  const int wm = (wv & 1) << 6, wn = (wv >> 1) << 6;
  const int m16 = lane & 15, quad = lane >> 4;

  if (atomicMode) {
    const int* ide = idx + e * BTOK;
#pragma unroll
    for (int mt = 0; mt < 4; ++mt) {
      const int row = tileM + wm + mt * 16 + quad * 4;
      const int o0 = ide[row], o1 = ide[row + 1], o2 = ide[row + 2], o3 = ide[row + 3];
#pragma unroll
      for (int nt = 0; nt < 4; ++nt) {
        const int col = tileN + wn + nt * 16 + m16;
        f32x4 v = acc[mt][nt];
        unsafeAtomicAdd(&out[(size_t)o0 * DD + col], v[0]);
        unsafeAtomicAdd(&out[(size_t)o1 * DD + col], v[1]);
        unsafeAtomicAdd(&out[(size_t)o2 * DD + col], v[2]);
        unsafeAtomicAdd(&out[(size_t)o3 * DD + col], v[3]);
      }
    }
  } else {
    float* oz = oE + (size_t)blockIdx.z * BTOK * DD;
#pragma unroll
    for (int mt = 0; mt < 4; ++mt) {
      const int row = tileM + wm + mt * 16 + quad * 4;
#pragma unroll
      for (int nt = 0; nt < 4; ++nt) {
        const int col = tileN + wn + nt * 16 + m16;
        f32x4 v = acc[mt][nt];
        oz[(size_t)(row + 0) * DD + col] = v[0];
        oz[(size_t)(row + 1) * DD + col] = v[1];
        oz[(size_t)(row + 2) * DD + col] = v[2];
        oz[(size_t)(row + 3) * DD + col] = v[3];
      }
    }
  }
}

// ---------------------------------------------------------------------------
// Scatter-add: out[idx[p]][:] += sum_z oE[z][p][:]  for p < n (exact count).
// Non-atomic: idx injective per expert. 256 blocks x 32 rows.
// ---------------------------------------------------------------------------
__global__ __launch_bounds__(256) void scatter_kernel(
    const float* __restrict__ oE, const int* __restrict__ idx,
    const int* __restrict__ nArr, float* __restrict__ out,
    int e, int zSplit) {
  const int n = nArr[4 + e];
  const int tid = threadIdx.x;
  for (int j = 0; j < 32; ++j) {
    const int row = blockIdx.x * 32 + j;
    if (row >= n) return;                       // block-uniform
    const int tok = idx[e * BTOK + row];
    f32x4 v = ((const f32x4*)(oE + (size_t)row * DD))[tid];
    if (zSplit == 2)
      v += ((const f32x4*)(oE + (size_t)BTOK * DD + (size_t)row * DD))[tid];
    f32x4* po = (f32x4*)(out + (size_t)tok * DD);
    po[tid] += v;
  }
}

// ---------------------------------------------------------------------------
// Gather x rows into dense compact xcomp[p] = xb[idx[p]]; zero pad rows.
// 256 blocks x 32 rows; each row = 128 x 16B chunks.
// ---------------------------------------------------------------------------
__global__ __launch_bounds__(256) void gatherx_kernel(
    const unsigned short* __restrict__ xb, const int* __restrict__ idx,
    const int* __restrict__ nArr, unsigned short* __restrict__ xcomp, int e) {
  const int np = nArr[e], n = nArr[4 + e];
  const int base = blockIdx.x * 32;
  if (base >= np) return;
  const int tid = threadIdx.x;
  // 32 rows * 128 chunks = 4096 chunk tasks / 256 threads = 16 iters
  for (int it = 0; it < 16; ++it) {
    const int cidx = it * 256 + tid;
    const int r = cidx >> 7, ch = cidx & 127;   // chunk of 8 shorts
    const int p = base + r;
    s16x8 v;
    if (p < n) {
      const int tok = idx[e * BTOK + p];
      v = ((const s16x8*)(xb + (size_t)tok * DD))[ch];
    } else {
      v = s16x8{0, 0, 0, 0, 0, 0, 0, 0};
    }
    ((s16x8*)(xcomp + (size_t)p * DD))[ch] = v;
  }
}

// ---------------------------------------------------------------------------
// Per-token: u, per-expert weights cE; out init with b2 term; x -> bf16.
// ---------------------------------------------------------------------------
__global__ __launch_bounds__(256) void u_kernel(
    const float* __restrict__ x, const float* __restrict__ Wu,
    const float* __restrict__ bu, const float* __restrict__ b2,
    float* __restrict__ cE, float* __restrict__ out,
    unsigned short* __restrict__ xb) {
  const int tok = blockIdx.x;
  const int tid = threadIdx.x;
  const float* xr = x + (size_t)tok * DD;

  f32x4 xv = ((const f32x4*)xr)[tid];
  f32x4 wv = ((const f32x4*)Wu)[tid];

  u16x4 o = {f2bf(xv[0]), f2bf(xv[1]), f2bf(xv[2]), f2bf(xv[3])};
  ((u16x4*)(xb + (size_t)tok * DD))[tid] = o;

  float s = xv[0] * wv[0] + xv[1] * wv[1] + xv[2] * wv[2] + xv[3] * wv[3];
#pragma unroll
  for (int off = 32; off > 0; off >>= 1) s += __shfl_down(s, off);

  __shared__ float red[4];
  __shared__ float cL[4];
  if ((tid & 63) == 0) red[tid >> 6] = s;
  __syncthreads();
  if (tid == 0) {
    float dot = red[0] + red[1] + red[2] + red[3] + bu[0];
    float u = 1.f / (1.f + expf(-dot));
    float kf = ceilf(u * 4.f);
    kf = fminf(fmaxf(kf, 1.f), 4.f);
    int k = (int)kf;
    int s4 = tok & 3;
#pragma unroll
    for (int e = 0; e < EE; ++e) {
      int i = ((e - s4) & 3) + 1;
      float ce = (i <= k) ? (u / (float)i) : 0.f;
      cL[e] = ce;
      cE[e * BTOK + tok] = ce;
    }
  }
  __syncthreads();
  const float c0 = cL[0], c1 = cL[1], c2 = cL[2], c3 = cL[3];
#pragma unroll
  for (int d = tid; d < DD; d += 256)
    out[(size_t)tok * DD + d] =
        c0 * b2[d] + c1 * b2[DD + d] + c2 * b2[2 * DD + d] + c3 * b2[3 * DD + d];
}

// ---------------------------------------------------------------------------
// Stable per-expert compaction (1024 threads; thread scans 8 tokens).
// nArr[e]=npad (mult of 128), nArr[4+e]=n exact. Pad idx/sc rows zeroed.
// ---------------------------------------------------------------------------
__global__ __launch_bounds__(1024) void compact_kernel(
    const float* __restrict__ cE, int* __restrict__ idx,
    float* __restrict__ sc, int* __restrict__ nArr) {
  const int e = blockIdx.x;
  const int tid = threadIdx.x;
  const float* ce = cE + e * BTOK;

  int cnt = 0;
#pragma unroll
  for (int j = 0; j < 8; ++j) cnt += (ce[tid * 8 + j] > 0.f) ? 1 : 0;

  const int lane = tid & 63, wvi = tid >> 6;
  int inc = cnt;
#pragma unroll
  for (int off = 1; off < 64; off <<= 1) {
    int v = __shfl_up(inc, off);
    if (lane >= off) inc += v;
  }
  __shared__ int wsum[16];
  if (lane == 63) wsum[wvi] = inc;
  __syncthreads();
  int base = 0;
  for (int w = 0; w < wvi; ++w) base += wsum[w];
  int pos = base + inc - cnt;

#pragma unroll
  for (int j = 0; j < 8; ++j) {
    float v = ce[tid * 8 + j];
    if (v > 0.f) {
      idx[e * BTOK + pos] = tid * 8 + j;
      sc[e * BTOK + pos] = v;
      ++pos;
    }
  }
  __syncthreads();
  int n = 0;
  for (int w = 0; w < 16; ++w) n += wsum[w];
  const int np = (n + 127) & ~127;
  if (tid == 0) { nArr[e] = np; nArr[4 + e] = n; }
  for (int p = n + tid; p < np; p += 1024) {
    idx[e * BTOK + p] = 0;
    sc[e * BTOK + p] = 0.f;
  }
}

// ---------------------------------------------------------------------------
// Transpose-convert: src [E][R][C] f32 -> dst [E][C][R] bf16.
// ---------------------------------------------------------------------------
__global__ __launch_bounds__(256) void tpose_kernel(const float* __restrict__ src,
                                                    unsigned short* __restrict__ dst,
                                                    int R, int C) {
  __shared__ float tile[32][33];
  const int e = blockIdx.z;
  const int r0 = blockIdx.y * 32, c0 = blockIdx.x * 32;
  const int tx = threadIdx.x & 31, ty = threadIdx.x >> 5;
  const float* s = src + (size_t)e * R * C;
  unsigned short* d = dst + (size_t)e * C * R;
#pragma unroll
  for (int j = 0; j < 32; j += 8)
    tile[ty + j][tx] = s[(size_t)(r0 + ty + j) * C + (c0 + tx)];
  __syncthreads();
#pragma unroll
  for (int j = 0; j < 32; j += 8)
    d[(size_t)(c0 + ty + j) * R + (r0 + tx)] = f2bf(tile[tx][ty + j]);
}

// ---------------------------------------------------------------------------
extern "C" void kernel_launch(void* const* d_in, const int* in_sizes, int n_in,
                              void* d_out, int out_size, void* d_ws, size_t ws_size,
                              hipStream_t stream) {
  const float* x  = (const float*)d_in[0];
  const float* W1 = (const float*)d_in[1];
  const float* b1 = (const float*)d_in[2];
  const float* W2 = (const float*)d_in[3];
  const float* b2 = (const float*)d_in[4];
  const float* Wu = (const float*)d_in[5];
  const float* bu = (const float*)d_in[6];
  float* out = (float*)d_out;

  // workspace layout
  char* w = (char*)d_ws;
  unsigned short* xb  = (unsigned short*)w;  w += (size_t)BTOK * DD * 2;     // 16.78 MB
  unsigned short* W1T = (unsigned short*)w;  w += (size_t)EE * DD * FF * 2;  // 33.55 MB
  unsigned short* W2T = (unsigned short*)w;  w += (size_t)EE * FF * DD * 2;  // 33.55 MB
  float* cE  = (float*)w;                    w += (size_t)EE * BTOK * 4;
  int*   idx = (int*)w;                      w += (size_t)EE * BTOK * 4;
  float* sc  = (float*)w;                    w += (size_t)EE * BTOK * 4;
  int*  nArr = (int*)w;                      w += 256;
  unsigned short* h = (unsigned short*)w;    w += (size_t)BTOK * FF * 2;     // 67.11 MB
  size_t baseUsed = (size_t)(w - (char*)d_ws);
  float* oE = (float*)w;                     // 1 or 2 slices of 33.55 MB
  unsigned short* xcomp = (unsigned short*)oE;  // aliases oE (disjoint lifetimes)

  const size_t SLICE = (size_t)BTOK * DD * 4;
  // ws_size constant per process -> branch is graph-safe
  const int mode = (ws_size >= baseUsed + 2 * SLICE) ? 2
                 : (ws_size >= baseUsed + SLICE)     ? 1 : 0;

  u_kernel<<<BTOK, 256, 0, stream>>>(x, Wu, bu, b2, cE, out, xb);
  tpose_kernel<<<dim3(FF / 32, DD / 32, EE), 256, 0, stream>>>(W1, W1T, DD, FF);
  tpose_kernel<<<dim3(DD / 32, FF / 32, EE), 256, 0, stream>>>(W2, W2T, FF, DD);
  compact_kernel<<<EE, 1024, 0, stream>>>(cE, idx, sc, nArr);

  for (int e = 0; e < EE; ++e) {
    if (mode >= 1) {
      const int z = (mode == 2) ? 2 : 1;
      gatherx_kernel<<<256, 256, 0, stream>>>(xb, idx, nArr, xcomp, e);
      gemm1_kernel<<<dim3(FF / 128, BTOK / 128), 256, 0, stream>>>(
          xcomp, (const int*)nullptr, W1T, b1, sc, nArr, h, e);
      gemm2_kernel<<<dim3(DD / 128, BTOK / 128, z), 256, 0, stream>>>(
          h, W2T, idx, nArr, oE, out, e, FF / z, 0);
      scatter_kernel<<<256, 256, 0, stream>>>(oE, idx, nArr, out, e, z);
    } else {
      gemm1_kernel<<<dim3(FF / 128, BTOK / 128), 256, 0, stream>>>(
          xb, idx + e * BTOK, W1T, b1, sc, nArr, h, e);
      gemm2_kernel<<<dim3(DD / 128, BTOK / 128, 1), 256, 0, stream>>>(
          h, W2T, idx, nArr, oE, out, e, FF, 1);
    }
  }
}

// Round 5
// 1316.957 us; speedup vs baseline: 1.1054x; 1.1054x over previous
//
#include <hip/hip_runtime.h>

#define DEV __device__ __forceinline__

typedef __attribute__((ext_vector_type(8))) short s16x8;   // 8 bf16 (4 VGPRs) MFMA A/B frag
typedef __attribute__((ext_vector_type(4))) float f32x4;   // MFMA C/D frag
typedef __attribute__((ext_vector_type(4))) unsigned short u16x4;

#define BTOK 8192   // B*S
#define DD   1024
#define FF   4096
#define EE   4

// round-to-nearest-even f32 -> bf16 bits
DEV unsigned short f2bf(float f) {
  unsigned int u = __float_as_uint(f);
  unsigned int r = (u + 0x7FFFu + ((u >> 16) & 1u)) >> 16;
  return (unsigned short)r;
}

// async global->LDS, 16 bytes/lane; LDS dest = wave-uniform base + lane*16
DEV void gld_lds16(const void* g, void* l) {
  __builtin_amdgcn_global_load_lds(
      (const __attribute__((address_space(1))) unsigned int*)g,
      (__attribute__((address_space(3))) unsigned int*)l,
      16, 0, 0);
}

// XCD-locality swizzle: flat block id F, N-tile count nX (gridDim.x).
// r=F&7 pins the XCD (flat%8 round-robin heuristic); all nX blocks sharing an
// A-row-tile get the same r -> same XCD -> A-tile fetched once per XCD.
// tileM_idx = (q/nX)*8 + r  (rows interleaved mod 8 so inactive tail rows
// spread evenly over XCDs), tileN_idx = q%nX. Bijective.
DEV void swizzle_tiles(int nX, int& tMi, int& tNi) {
  const int F = blockIdx.x + nX * blockIdx.y;
  const int r = F & 7, q = F >> 3;
  tMi = (q / nX) * 8 + r;
  tNi = q % nX;
}

// ---------------------------------------------------------------------------
// 128x128 bf16 MFMA tile mainloop, BK=64 (2 MFMA k-steps per barrier pair).
// Group-major LDS layout: chunk c = g*128 + r holds row r, k-group g (8 elems);
// fragment read = (kstep*4+quad)*2048B + row*16B -> 256B contiguous per
// 16-lane phase => conflict-free (verified 0 conflicts R3/R4).
// A rows optionally gathered via idxA (per-lane global addresses are free).
// ---------------------------------------------------------------------------
DEV void gemm_tile(const unsigned short* __restrict__ A, const int* idxA, int ldA,
                   const unsigned short* __restrict__ B, int ldB,
                   int kStart, int kLen, int tileM, int tileN,
                   unsigned short* As, unsigned short* Bs,
                   f32x4 (&acc)[4][4]) {
  const int t    = threadIdx.x;
  const int lane = t & 63;
  const int wv   = t >> 6;
  const int wm   = (wv & 1) << 6;
  const int wn   = (wv >> 1) << 6;
  const int m16  = lane & 15;
  const int quad = lane >> 4;

  const int r  = t & 127;   // staged row (same for all 4 chunks of this thread)
  const int g0 = t >> 7;    // k-group base; chunks at g0, g0+2, g0+4, g0+6

  const int rowA = idxA ? idxA[tileM + r] : (tileM + r);
  const unsigned short* A0 = A + (size_t)rowA * ldA + kStart + g0 * 8;
  const unsigned short* B0 = B + (size_t)(tileN + r) * ldB + kStart + g0 * 8;

  for (int k0 = 0; k0 < kLen; k0 += 64) {
    __syncthreads();               // protect LDS from previous iteration's readers
#pragma unroll
    for (int j = 0; j < 4; ++j) {  // global k-group g0+2j == LDS chunk (t+256j)>>7
      gld_lds16(A0 + k0 + j * 16, As + (t + 256 * j) * 8);
      gld_lds16(B0 + k0 + j * 16, Bs + (t + 256 * j) * 8);
    }
    __syncthreads();               // drains vmcnt -> staged data visible

#pragma unroll
    for (int s = 0; s < 2; ++s) {  // two K=32 MFMA steps per staged BK=64
      s16x8 aF[4], bF[4];
#pragma unroll
      for (int i = 0; i < 4; ++i) {
        aF[i] = *(const s16x8*)(As + ((s * 4 + quad) << 10) + ((wm + i * 16 + m16) << 3));
        bF[i] = *(const s16x8*)(Bs + ((s * 4 + quad) << 10) + ((wn + i * 16 + m16) << 3));
      }
#pragma unroll
      for (int mt = 0; mt < 4; ++mt)
#pragma unroll
        for (int nt = 0; nt < 4; ++nt)
          acc[mt][nt] = __builtin_amdgcn_mfma_f32_16x16x32_bf16(
              aF[mt], bF[nt], acc[mt][nt], 0, 0, 0);
    }
  }
}

// ---------------------------------------------------------------------------
// GEMM1 (gathered): h[p][f] = bf16( sc[p] * relu( xb[idx[p]]@W1[e] + b1[e][f] ) )
// ---------------------------------------------------------------------------
__global__ __launch_bounds__(256) void gemm1_kernel(
    const unsigned short* __restrict__ xb,   // [BTOK][DD]
    const int* __restrict__ idx,             // [EE][BTOK] compact token idx
    const unsigned short* __restrict__ W1T,  // [EE][FF][DD]
    const float* __restrict__ b1,            // [EE][FF]
    const float* __restrict__ sc,            // [EE][BTOK] compact scales
    const int* __restrict__ nArr,            // [0..3]=npad, [4..7]=n
    unsigned short* __restrict__ h,          // [BTOK][FF]
    int e) {
  __shared__ __attribute__((aligned(16))) unsigned short As[128 * 64];
  __shared__ __attribute__((aligned(16))) unsigned short Bs[128 * 64];

  int tMi, tNi;
  swizzle_tiles(FF / 128, tMi, tNi);         // gridDim.x = 32
  const int np    = nArr[e];
  const int tileM = tMi * 128;
  if (tileM >= np) return;                   // block-uniform early exit
  const int tileN = tNi * 128;

  f32x4 acc[4][4];
#pragma unroll
  for (int i = 0; i < 4; ++i)
#pragma unroll
    for (int j = 0; j < 4; ++j) acc[i][j] = f32x4{0.f, 0.f, 0.f, 0.f};

  gemm_tile(xb, idx + e * BTOK, DD, W1T + (size_t)e * FF * DD, DD,
            0, DD, tileM, tileN, As, Bs, acc);

  const int t = threadIdx.x;
  const int lane = t & 63, wv = t >> 6;
  const int wm = (wv & 1) << 6, wn = (wv >> 1) << 6;
  const int m16 = lane & 15, quad = lane >> 4;
  const float* b1e = b1 + e * FF;
  const float* sce = sc + e * BTOK;

#pragma unroll
  for (int mt = 0; mt < 4; ++mt) {
    const int row = tileM + wm + mt * 16 + quad * 4;   // C/D: row = quad*4 + reg
    const f32x4 cv = *(const f32x4*)(sce + row);
#pragma unroll
    for (int nt = 0; nt < 4; ++nt) {
      const int col = tileN + wn + nt * 16 + m16;      // C/D: col = lane&15
      const float bb = b1e[col];
      f32x4 v = acc[mt][nt];
      h[(size_t)(row + 0) * FF + col] = f2bf(fmaxf(v[0] + bb, 0.f) * cv[0]);
      h[(size_t)(row + 1) * FF + col] = f2bf(fmaxf(v[1] + bb, 0.f) * cv[1]);
      h[(size_t)(row + 2) * FF + col] = f2bf(fmaxf(v[2] + bb, 0.f) * cv[2]);
      h[(size_t)(row + 3) * FF + col] = f2bf(fmaxf(v[3] + bb, 0.f) * cv[3]);
    }
  }
}

// ---------------------------------------------------------------------------
// GEMM2: compact rows, K split into zSplit slices (grid z).
// atomicMode=0: plain stores into oE[z][p][DD]; =1: unsafeAtomicAdd to out.
// ---------------------------------------------------------------------------
__global__ __launch_bounds__(256) void gemm2_kernel(
    const unsigned short* __restrict__ h,    // [BTOK][FF]
    const unsigned short* __restrict__ W2T,  // [EE][DD][FF]
    const int* __restrict__ idx,             // [EE][BTOK]
    const int* __restrict__ nArr,
    float* __restrict__ oE,                  // [zSplit][BTOK][DD]
    float* __restrict__ out,                 // [BTOK][DD] (mode 0)
    int e, int kLen, int atomicMode) {
  __shared__ __attribute__((aligned(16))) unsigned short As[128 * 64];
  __shared__ __attribute__((aligned(16))) unsigned short Bs[128 * 64];

  int tMi, tNi;
  swizzle_tiles(DD / 128, tMi, tNi);         // gridDim.x = 8
  const int np    = nArr[e];
  const int tileM = tMi * 128;
  if (tileM >= np) return;
  const int tileN  = tNi * 128;
  const int kStart = blockIdx.z * kLen;

  f32x4 acc[4][4];
#pragma unroll
  for (int i = 0; i < 4; ++i)
#pragma unroll
    for (int j = 0; j < 4; ++j) acc[i][j] = f32x4{0.f, 0.f, 0.f, 0.f};

  gemm_tile(h, (const int*)nullptr, FF, W2T + (size_t)e * DD * FF, FF,
            kStart, kLen, tileM, tileN, As, Bs, acc);

  const int t = threadIdx.x;
  const int lane = t & 63, wv = t >> 6;
  const int wm = (wv & 1) << 6, wn = (wv >> 1) << 6;
  const int m16 = lane & 15, quad = lane >> 4;

  if (atomicMode) {
    const int* ide = idx + e * BTOK;
#pragma unroll
    for (int mt = 0; mt < 4; ++mt) {
      const int row = tileM + wm + mt * 16 + quad * 4;
      const int o0 = ide[row], o1 = ide[row + 1], o2 = ide[row + 2], o3 = ide[row + 3];
#pragma unroll
      for (int nt = 0; nt < 4; ++nt) {
        const int col = tileN + wn + nt * 16 + m16;
        f32x4 v = acc[mt][nt];
        unsafeAtomicAdd(&out[(size_t)o0 * DD + col], v[0]);
        unsafeAtomicAdd(&out[(size_t)o1 * DD + col], v[1]);
        unsafeAtomicAdd(&out[(size_t)o2 * DD + col], v[2]);
        unsafeAtomicAdd(&out[(size_t)o3 * DD + col], v[3]);
      }
    }
  } else {
    float* oz = oE + (size_t)blockIdx.z * BTOK * DD;
#pragma unroll
    for (int mt = 0; mt < 4; ++mt) {
      const int row = tileM + wm + mt * 16 + quad * 4;
#pragma unroll
      for (int nt = 0; nt < 4; ++nt) {
        const int col = tileN + wn + nt * 16 + m16;
        f32x4 v = acc[mt][nt];
        oz[(size_t)(row + 0) * DD + col] = v[0];
        oz[(size_t)(row + 1) * DD + col] = v[1];
        oz[(size_t)(row + 2) * DD + col] = v[2];
        oz[(size_t)(row + 3) * DD + col] = v[3];
      }
    }
  }
}

// ---------------------------------------------------------------------------
// Scatter-add: out[idx[p]][:] += sum_z oE[z][p][:]  for p < n (exact count).
// Non-atomic: idx injective per expert.
// ---------------------------------------------------------------------------
__global__ __launch_bounds__(256) void scatter_kernel(
    const float* __restrict__ oE, const int* __restrict__ idx,
    const int* __restrict__ nArr, float* __restrict__ out,
    int e, int zSplit) {
  const int n = nArr[4 + e];
  const int tid = threadIdx.x;
  for (int j = 0; j < 32; ++j) {
    const int row = blockIdx.x * 32 + j;
    if (row >= n) return;                       // block-uniform
    const int tok = idx[e * BTOK + row];
    f32x4 v = ((const f32x4*)(oE + (size_t)row * DD))[tid];
    if (zSplit == 2)
      v += ((const f32x4*)(oE + (size_t)BTOK * DD + (size_t)row * DD))[tid];
    f32x4* po = (f32x4*)(out + (size_t)tok * DD);
    po[tid] += v;
  }
}

// ---------------------------------------------------------------------------
// Per-token: u, per-expert weights cE; out init with b2 term; x -> bf16.
// ---------------------------------------------------------------------------
__global__ __launch_bounds__(256) void u_kernel(
    const float* __restrict__ x, const float* __restrict__ Wu,
    const float* __restrict__ bu, const float* __restrict__ b2,
    float* __restrict__ cE, float* __restrict__ out,
    unsigned short* __restrict__ xb) {
  const int tok = blockIdx.x;
  const int tid = threadIdx.x;
  const float* xr = x + (size_t)tok * DD;

  f32x4 xv = ((const f32x4*)xr)[tid];
  f32x4 wv = ((const f32x4*)Wu)[tid];

  u16x4 o = {f2bf(xv[0]), f2bf(xv[1]), f2bf(xv[2]), f2bf(xv[3])};
  ((u16x4*)(xb + (size_t)tok * DD))[tid] = o;

  float s = xv[0] * wv[0] + xv[1] * wv[1] + xv[2] * wv[2] + xv[3] * wv[3];
#pragma unroll
  for (int off = 32; off > 0; off >>= 1) s += __shfl_down(s, off);

  __shared__ float red[4];
  __shared__ float cL[4];
  if ((tid & 63) == 0) red[tid >> 6] = s;
  __syncthreads();
  if (tid == 0) {
    float dot = red[0] + red[1] + red[2] + red[3] + bu[0];
    float u = 1.f / (1.f + expf(-dot));
    float kf = ceilf(u * 4.f);
    kf = fminf(fmaxf(kf, 1.f), 4.f);
    int k = (int)kf;
    int s4 = tok & 3;   // s = tok % 2048; s % 4 == tok % 4
#pragma unroll
    for (int e = 0; e < EE; ++e) {
      int i = ((e - s4) & 3) + 1;
      float ce = (i <= k) ? (u / (float)i) : 0.f;
      cL[e] = ce;
      cE[e * BTOK + tok] = ce;
    }
  }
  __syncthreads();
  const float c0 = cL[0], c1 = cL[1], c2 = cL[2], c3 = cL[3];
#pragma unroll
  for (int d = tid; d < DD; d += 256)
    out[(size_t)tok * DD + d] =
        c0 * b2[d] + c1 * b2[DD + d] + c2 * b2[2 * DD + d] + c3 * b2[3 * DD + d];
}

// ---------------------------------------------------------------------------
// Stable per-expert compaction (1024 threads; thread scans 8 tokens).
// ---------------------------------------------------------------------------
__global__ __launch_bounds__(1024) void compact_kernel(
    const float* __restrict__ cE, int* __restrict__ idx,
    float* __restrict__ sc, int* __restrict__ nArr) {
  const int e = blockIdx.x;
  const int tid = threadIdx.x;
  const float* ce = cE + e * BTOK;

  int cnt = 0;
#pragma unroll
  for (int j = 0; j < 8; ++j) cnt += (ce[tid * 8 + j] > 0.f) ? 1 : 0;

  const int lane = tid & 63, wvi = tid >> 6;
  int inc = cnt;
#pragma unroll
  for (int off = 1; off < 64; off <<= 1) {
    int v = __shfl_up(inc, off);
    if (lane >= off) inc += v;
  }
  __shared__ int wsum[16];
  if (lane == 63) wsum[wvi] = inc;
  __syncthreads();
  int base = 0;
  for (int w = 0; w < wvi; ++w) base += wsum[w];
  int pos = base + inc - cnt;

#pragma unroll
  for (int j = 0; j < 8; ++j) {
    float v = ce[tid * 8 + j];
    if (v > 0.f) {
      idx[e * BTOK + pos] = tid * 8 + j;
      sc[e * BTOK + pos] = v;
      ++pos;
    }
  }
  __syncthreads();
  int n = 0;
  for (int w = 0; w < 16; ++w) n += wsum[w];
  const int np = (n + 127) & ~127;
  if (tid == 0) { nArr[e] = np; nArr[4 + e] = n; }
  for (int p = n + tid; p < np; p += 1024) {
    idx[e * BTOK + p] = 0;
    sc[e * BTOK + p] = 0.f;
  }
}

// ---------------------------------------------------------------------------
// Transpose-convert: src [E][R][C] f32 -> dst [E][C][R] bf16.
// ---------------------------------------------------------------------------
__global__ __launch_bounds__(256) void tpose_kernel(const float* __restrict__ src,
                                                    unsigned short* __restrict__ dst,
                                                    int R, int C) {
  __shared__ float tile[32][33];
  const int e = blockIdx.z;
  const int r0 = blockIdx.y * 32, c0 = blockIdx.x * 32;
  const int tx = threadIdx.x & 31, ty = threadIdx.x >> 5;
  const float* s = src + (size_t)e * R * C;
  unsigned short* d = dst + (size_t)e * C * R;
#pragma unroll
  for (int j = 0; j < 32; j += 8)
    tile[ty + j][tx] = s[(size_t)(r0 + ty + j) * C + (c0 + tx)];
  __syncthreads();
#pragma unroll
  for (int j = 0; j < 32; j += 8)
    d[(size_t)(c0 + ty + j) * R + (r0 + tx)] = f2bf(tile[tx][ty + j]);
}

// ---------------------------------------------------------------------------
extern "C" void kernel_launch(void* const* d_in, const int* in_sizes, int n_in,
                              void* d_out, int out_size, void* d_ws, size_t ws_size,
                              hipStream_t stream) {
  const float* x  = (const float*)d_in[0];
  const float* W1 = (const float*)d_in[1];
  const float* b1 = (const float*)d_in[2];
  const float* W2 = (const float*)d_in[3];
  const float* b2 = (const float*)d_in[4];
  const float* Wu = (const float*)d_in[5];
  const float* bu = (const float*)d_in[6];
  float* out = (float*)d_out;

  // workspace layout (identical to R4: mode-2 total 218.50 MB, known to fit)
  char* w = (char*)d_ws;
  unsigned short* xb  = (unsigned short*)w;  w += (size_t)BTOK * DD * 2;     // 16.78 MB
  unsigned short* W1T = (unsigned short*)w;  w += (size_t)EE * DD * FF * 2;  // 33.55 MB
  unsigned short* W2T = (unsigned short*)w;  w += (size_t)EE * FF * DD * 2;  // 33.55 MB
  float* cE  = (float*)w;                    w += (size_t)EE * BTOK * 4;
  int*   idx = (int*)w;                      w += (size_t)EE * BTOK * 4;
  float* sc  = (float*)w;                    w += (size_t)EE * BTOK * 4;
  int*  nArr = (int*)w;                      w += 256;
  unsigned short* h = (unsigned short*)w;    w += (size_t)BTOK * FF * 2;     // 67.11 MB
  size_t baseUsed = (size_t)(w - (char*)d_ws);
  float* oE = (float*)w;                     // 1 or 2 slices of 33.55 MB

  const size_t SLICE = (size_t)BTOK * DD * 4;
  // ws_size constant per process -> branch is graph-safe
  const int mode = (ws_size >= baseUsed + 2 * SLICE) ? 2
                 : (ws_size >= baseUsed + SLICE)     ? 1 : 0;

  u_kernel<<<BTOK, 256, 0, stream>>>(x, Wu, bu, b2, cE, out, xb);
  tpose_kernel<<<dim3(FF / 32, DD / 32, EE), 256, 0, stream>>>(W1, W1T, DD, FF);
  tpose_kernel<<<dim3(DD / 32, FF / 32, EE), 256, 0, stream>>>(W2, W2T, FF, DD);
  compact_kernel<<<EE, 1024, 0, stream>>>(cE, idx, sc, nArr);

  for (int e = 0; e < EE; ++e) {
    gemm1_kernel<<<dim3(FF / 128, BTOK / 128), 256, 0, stream>>>(
        xb, idx, W1T, b1, sc, nArr, h, e);
    if (mode >= 1) {
      const int z = (mode == 2) ? 2 : 1;
      gemm2_kernel<<<dim3(DD / 128, BTOK / 128, z), 256, 0, stream>>>(
          h, W2T, idx, nArr, oE, out, e, FF / z, 0);
      scatter_kernel<<<256, 256, 0, stream>>>(oE, idx, nArr, out, e, z);
    } else {
      gemm2_kernel<<<dim3(DD / 128, BTOK / 128, 4), 256, 0, stream>>>(
          h, W2T, idx, nArr, oE, out, e, FF / 4, 1);
    }
  }
}